// Round 11
// baseline (95.737 us; speedup 1.0000x reference)
//
#include <hip/hip_runtime.h>

#define CLS   160          // CLASS_NUM * NUM_PRED
#define TOPKN 1000
#define N0 147456
#define N1 36864
#define N2 9216
#define N3 2304
#define N4 576
#define NROWS (N0 + N1 + N2 + N3)
#define BD1 N0
#define BD2 (N0 + N1)
#define BD3 (N0 + N1 + N2)
#define NBINS 65536
#define CAND_CAP 2048
#define PMAX 16            // max passers per thread (E~1.04, P(>16) ~ 1e-13)

__device__ __forceinline__ unsigned sortable(float f) {
    unsigned u = __float_as_uint(f);
    return (u & 0x80000000u) ? ~u : (u | 0x80000000u);
}

// ---------------------------------------------------------------------------
// Shared epilogue body: one 256-thread block emits one output row group
// (80 classes x 12 floats) for anchor idx of level (A,C,R) into out row s.
// ---------------------------------------------------------------------------
__device__ __forceinline__ void epilogue_row(
    const float* A, const float* C, const float* R, int idx, int s,
    float* out, float* sc, float* bb, int tt)
{
    const float* cp = C + (size_t)idx * CLS;
    if (tt < CLS) {
        float x = cp[tt];
        sc[tt] = 1.0f / (1.0f + __expf(-x));
    }
    if (tt == 192) {
        const float* ap = A + (size_t)idx * 4;
        const float* rp = R + (size_t)idx * 8;
        float x1 = ap[0], y1 = ap[1], x2 = ap[2], y2 = ap[3];
        float w  = x2 - x1 + 1.0f, h = y2 - y1 + 1.0f;
        float cx = x1 + 0.5f * w,  cy = y1 + 0.5f * h;
        #pragma unroll
        for (int p = 0; p < 2; ++p) {
            float pcx = cx + rp[4 * p + 0] * w;
            float pcy = cy + rp[4 * p + 1] * h;
            float pw  = w * __expf(rp[4 * p + 2]);
            float ph  = h * __expf(rp[4 * p + 3]);
            bb[4 * p + 0] = pcx - 0.5f * pw;
            bb[4 * p + 1] = pcy - 0.5f * ph;
            bb[4 * p + 2] = pcx + 0.5f * pw;
            bb[4 * p + 3] = pcy + 0.5f * ph;
        }
    }
    __syncthreads();
    float4* orow = (float4*)(out + (size_t)s * 960);
    if (tt < 240) {
        int j = tt / 3, part = tt % 3;
        float tag = (float)(j + 1);
        float4 v;
        if (part == 0)      v = make_float4(bb[0], bb[1], bb[2], bb[3]);
        else if (part == 1) v = make_float4(sc[j], tag, bb[4], bb[5]);
        else                v = make_float4(bb[6], bb[7], sc[80 + j], tag);
        orow[tt] = v;
    }
}

// ---------------------------------------------------------------------------
// K1: ruler keys (blocks 0..1529, proven) + fused level-4 epilogue (blocks
// 1530..2105 — depends only on inputs, so it rides along for free). Zeroes
// hist|coarse (266240 words <= threads).
// ---------------------------------------------------------------------------
__global__ __launch_bounds__(256) void k_ruler(
    const float* __restrict__ c0, const float* __restrict__ c1,
    const float* __restrict__ c2, const float* __restrict__ c3,
    const float* __restrict__ a4, const float* __restrict__ c4,
    const float* __restrict__ r4,
    unsigned* __restrict__ keys, unsigned* __restrict__ hist,
    float* __restrict__ out)
{
    int tid = blockIdx.x * 256 + threadIdx.x;
    if (tid < 4 * NBINS + 4096) hist[tid] = 0;

    if (blockIdx.x >= 1530) {            // fused level-4 epilogue
        __shared__ float sc[CLS];
        __shared__ float bb[8];
        int s4 = blockIdx.x - 1530;      // 0..575
        epilogue_row(a4, c4, r4, s4, 4 * TOPKN + s4, out, sc, bb, threadIdx.x);
        return;
    }

    int r0 = blockIdx.x << 7;
    const float* cb; int lr0;
    if (r0 < BD1)      { cb = c0; lr0 = r0; }
    else if (r0 < BD2) { cb = c1; lr0 = r0 - BD1; }
    else if (r0 < BD3) { cb = c2; lr0 = r0 - BD2; }
    else               { cb = c3; lr0 = r0 - BD3; }

    int wv   = threadIdx.x >> 6;
    int lane = threadIdx.x & 63;
    int sub  = lane >> 3;
    int col  = lane & 7;
    #pragma unroll
    for (int i = 0; i < 4; ++i) {
        int rrel = wv * 32 + i * 8 + sub;
        const float4* p = (const float4*)cb + (size_t)(lr0 + rrel) * 40 + col;
        float m = -3.4e38f;
        #pragma unroll
        for (int k = 0; k < 5; ++k) {
            float4 v = p[8 * k];
            m = fmaxf(m, fmaxf(fmaxf(v.x, v.y), fmaxf(v.z, v.w)));
        }
        m = fmaxf(m, __shfl_xor(m, 1));
        m = fmaxf(m, __shfl_xor(m, 2));
        m = fmaxf(m, __shfl_xor(m, 4));
        if (col == 0) keys[r0 + rrel] = sortable(m);
    }
}

// ---------------------------------------------------------------------------
// K2: chunked segment histogram (proven). 1024 blocks x 256: hist bins +
// coarse per-64-bin chunk sums.
// ---------------------------------------------------------------------------
__global__ __launch_bounds__(256) void k_hist(const unsigned* __restrict__ keys,
                                              unsigned* __restrict__ hist,
                                              unsigned* __restrict__ coarse)
{
    int b        = blockIdx.x;
    int level    = b >> 8;
    unsigned seg = (b >> 4) & 15;
    int chunk    = b & 15;
    __shared__ unsigned cnt[4096];
    for (int i = threadIdx.x; i < 4096; i += 256) cnt[i] = 0;
    __syncthreads();
    int base, n;
    switch (level) {
        case 0:  base = 0;   n = N0; break;
        case 1:  base = BD1; n = N1; break;
        case 2:  base = BD2; n = N2; break;
        default: base = BD3; n = N3; break;
    }
    int q = n >> 4;
    const uint4* kp = (const uint4*)(keys + base + chunk * q);
    int nv = q >> 2;
    for (int i = threadIdx.x; i < nv; i += 256) {
        uint4 k = kp[i];
        unsigned b0 = k.x >> 16, b1 = k.y >> 16, b2 = k.z >> 16, b3 = k.w >> 16;
        if ((b0 >> 12) == seg) atomicAdd(&cnt[b0 & 4095u], 1u);
        if ((b1 >> 12) == seg) atomicAdd(&cnt[b1 & 4095u], 1u);
        if ((b2 >> 12) == seg) atomicAdd(&cnt[b2 & 4095u], 1u);
        if ((b3 >> 12) == seg) atomicAdd(&cnt[b3 & 4095u], 1u);
    }
    __syncthreads();
    unsigned* h = hist + level * NBINS + (seg << 12);
    for (int i = threadIdx.x; i < 4096; i += 256) {
        unsigned c = cnt[i];
        if (c) atomicAdd(&h[i], c);
    }
    if (threadIdx.x < 64) {
        int j = threadIdx.x;
        unsigned s2 = 0;
        #pragma unroll 8
        for (int i = 0; i < 64; ++i) s2 += cnt[j * 64 + ((i + j) & 63)];
        if (s2) atomicAdd(&coarse[level * 1024 + (int)(seg << 6) + j], s2);
    }
}

// ---------------------------------------------------------------------------
// K3: fused decide+compact+rank, one block per level (R6 structure — best
// measured). Part B restructured for MLP: the old loop had a ballot + LDS
// atomic after EVERY uint4 load (load->ballot dependence chain = ~36 serial
// L2 round trips for level 0). Now: dependence-free streaming scan stashing
// passers in registers, then one block-wide scan assigns LDS slots.
// ---------------------------------------------------------------------------
__global__ __launch_bounds__(1024) void k_select(const unsigned* __restrict__ keys,
                                                 const unsigned* __restrict__ hist,
                                                 const unsigned* __restrict__ coarse,
                                                 unsigned* __restrict__ sel)
{
    int level = blockIdx.x;
    int t     = threadIdx.x;

    __shared__ unsigned s[1024];
    __shared__ unsigned long long a[CAND_CAP];
    __shared__ unsigned thr_s, chunk_s, cum0_s;

    // ---- A: threshold from coarse + one 64-bin refine (proven R6 math) ----
    s[t] = coarse[level * 1024 + t];
    __syncthreads();
    for (int off = 1; off < 1024; off <<= 1) {
        unsigned v   = s[t];
        unsigned add = (t + off < 1024) ? s[t + off] : 0u;
        __syncthreads();
        s[t] = v + add;
        __syncthreads();
    }
    if (s[t] >= TOPKN && (t == 1023 || s[t + 1] < TOPKN)) {
        chunk_s = (unsigned)t;
        cum0_s  = (t == 1023) ? 0u : s[t + 1];
    }
    __syncthreads();
    if (t < 64) {
        const unsigned* h = hist + level * NBINS;
        unsigned c = h[chunk_s * 64 + (unsigned)t];
        unsigned suf = c;
        #pragma unroll
        for (int off = 1; off < 64; off <<= 1) {
            unsigned v = __shfl_down(suf, off);
            if (t + off < 64) suf += v;
        }
        unsigned long long mask = __ballot(cum0_s + suf >= TOPKN);
        if (t == 0)
            thr_s = ((chunk_s << 6) + (63u - (unsigned)__clzll(mask))) << 16;
    }
    __syncthreads();
    unsigned thr = thr_s;

    // ---- B: streaming scan, passers to registers (full MLP) ----
    int base = (level == 0) ? 0 : (level == 1) ? BD1 : (level == 2) ? BD2 : BD3;
    int n    = (level == 0) ? N0 : (level == 1) ? N1 : (level == 2) ? N2 : N3;
    const uint4* kp = (const uint4*)(keys + base);
    int nv = n >> 2;
    unsigned pk[PMAX], pidx[PMAX];
    int pc = 0;
    for (int i = t; i < nv; i += 1024) {
        uint4 k4 = kp[i];
        if (k4.x >= thr && pc < PMAX) { pk[pc] = k4.x; pidx[pc] = 4 * i + 0; ++pc; }
        if (k4.y >= thr && pc < PMAX) { pk[pc] = k4.y; pidx[pc] = 4 * i + 1; ++pc; }
        if (k4.z >= thr && pc < PMAX) { pk[pc] = k4.z; pidx[pc] = 4 * i + 2; ++pc; }
        if (k4.w >= thr && pc < PMAX) { pk[pc] = k4.w; pidx[pc] = 4 * i + 3; ++pc; }
    }
    __syncthreads();
    s[t] = (unsigned)pc;
    __syncthreads();
    for (int off = 1; off < 1024; off <<= 1) {     // inclusive prefix scan
        unsigned v   = s[t];
        unsigned add = (t >= off) ? s[t - off] : 0u;
        __syncthreads();
        s[t] = v + add;
        __syncthreads();
    }
    unsigned my_base = s[t] - (unsigned)pc;
    unsigned cnt = s[1023];
    if (cnt > CAND_CAP) cnt = CAND_CAP;
    for (int j = 0; j < pc; ++j) {
        unsigned pos = my_base + (unsigned)j;
        if (pos < CAND_CAP)
            a[pos] = ((unsigned long long)pk[j] << 32) | (unsigned)~pidx[j];
    }
    __syncthreads();

    // ---- C: exact stable rank (descending key, ties ascending index) ----
    for (int i = t; i < (int)cnt; i += 1024) {
        unsigned long long mine = a[i];
        unsigned rank = 0;
        for (int j = 0; j < (int)cnt; ++j) rank += (a[j] > mine) ? 1u : 0u;
        if (rank < TOPKN)
            sel[level * TOPKN + rank] = ~(unsigned)(mine & 0xFFFFFFFFull);
    }
}

// ---------------------------------------------------------------------------
// K4: epilogue for ranked rows only (4000 blocks; level 4 done in k_ruler).
// ---------------------------------------------------------------------------
__global__ __launch_bounds__(256) void k_epilogue(
    const float* a0, const float* a1, const float* a2, const float* a3,
    const float* c0, const float* c1, const float* c2, const float* c3,
    const float* r0, const float* r1, const float* r2, const float* r3,
    const unsigned* __restrict__ sel, float* __restrict__ out)
{
    int s = blockIdx.x;
    int level = s / TOPKN;
    int idx   = (int)sel[s];
    const float *A, *C, *R;
    switch (level) {
        case 0: A = a0; C = c0; R = r0; break;
        case 1: A = a1; C = c1; R = r1; break;
        case 2: A = a2; C = c2; R = r2; break;
        default: A = a3; C = c3; R = r3; break;
    }
    __shared__ float sc[CLS];
    __shared__ float bb[8];
    epilogue_row(A, C, R, idx, s, out, sc, bb, threadIdx.x);
}

// ---------------------------------------------------------------------------
// Workspace (uint32 words):
//   keys[NROWS] | hist[4*NBINS] | coarse[4096] | sel[4*TOPKN]  (~1.8 MB)
// hist|coarse zeroed by k_ruler each call.
// ---------------------------------------------------------------------------
extern "C" void kernel_launch(void* const* d_in, const int* in_sizes, int n_in,
                              void* d_out, int out_size, void* d_ws, size_t ws_size,
                              hipStream_t stream)
{
    bool interleaved = (in_sizes[1] > 1000000);
    const float *A[5], *C[5], *R[5];
    for (int i = 0; i < 5; ++i) {
        if (interleaved) {
            A[i] = (const float*)d_in[3 * i + 0];
            C[i] = (const float*)d_in[3 * i + 1];
            R[i] = (const float*)d_in[3 * i + 2];
        } else {
            A[i] = (const float*)d_in[i];
            C[i] = (const float*)d_in[5 + i];
            R[i] = (const float*)d_in[10 + i];
        }
    }

    unsigned* keys   = (unsigned*)d_ws;
    unsigned* hist   = keys + NROWS;
    unsigned* coarse = hist + 4 * NBINS;
    unsigned* sel    = coarse + 4096;

    k_ruler<<<2106, 256, 0, stream>>>(C[0], C[1], C[2], C[3],
                                      A[4], C[4], R[4],
                                      keys, hist, (float*)d_out);
    k_hist<<<1024, 256, 0, stream>>>(keys, hist, coarse);
    k_select<<<4, 1024, 0, stream>>>(keys, hist, coarse, sel);
    k_epilogue<<<4 * TOPKN, 256, 0, stream>>>(A[0], A[1], A[2], A[3],
                                              C[0], C[1], C[2], C[3],
                                              R[0], R[1], R[2], R[3],
                                              sel, (float*)d_out);
}